// Round 1
// baseline (205.090 us; speedup 1.0000x reference)
//
#include <hip/hip_runtime.h>
#include <hip/hip_bf16.h>

#define N_PTS 16384
#define DIM   128

typedef __bf16 bf16x8 __attribute__((ext_vector_type(8)));
typedef float  f32x4  __attribute__((ext_vector_type(4)));

// Monotone map float -> uint so unsigned atomicMin == float min (handles negatives).
__device__ __forceinline__ unsigned fmap(float f) {
    unsigned u = __float_as_uint(f);
    return (u & 0x80000000u) ? ~u : (u | 0x80000000u);
}
__device__ __forceinline__ float funmap(unsigned u) {
    return __uint_as_float((u & 0x80000000u) ? (u & 0x7FFFFFFFu) : ~u);
}

// ---------------------------------------------------------------------------
// Kernel 1: per-row squared norms (fp32, matches reference exactly) + init the
// global min arrays. One wave per row, 4 waves/block, grid = 2*N/4.
// ---------------------------------------------------------------------------
__global__ void chamfer_prep(const float* __restrict__ A, const float* __restrict__ B,
                             float* __restrict__ a2, float* __restrict__ b2,
                             unsigned* __restrict__ rowmin, unsigned* __restrict__ colmin) {
    int wave = blockIdx.x * 4 + (threadIdx.x >> 6);
    int lane = threadIdx.x & 63;
    int isB  = wave >= N_PTS;
    int row  = isB ? (wave - N_PTS) : wave;
    const float* src = isB ? B : A;
    float2 v = *reinterpret_cast<const float2*>(&src[(size_t)row * DIM + lane * 2]);
    float s = v.x * v.x + v.y * v.y;
    #pragma unroll
    for (int off = 32; off; off >>= 1) s += __shfl_down(s, off);
    if (lane == 0) {
        if (isB) { b2[row] = s; colmin[row] = 0xFFFFFFFFu; }
        else     { a2[row] = s; rowmin[row] = 0xFFFFFFFFu; }
    }
}

// ---------------------------------------------------------------------------
// Kernel 2: fused 128x128-tile NT-GEMM (bf16 MFMA, fp32 acc) + dist epilogue +
// row/col min reduction. fp32 inputs are converted to bf16 during LDS staging.
// LDS layout is XOR-swizzled: byte = row*256 + ((kc*16) ^ ((row&7)<<4)).
// ---------------------------------------------------------------------------
__global__ __launch_bounds__(256, 2)
void chamfer_gemm_min(const float* __restrict__ A, const float* __restrict__ B,
                      const float* __restrict__ a2, const float* __restrict__ b2,
                      unsigned* __restrict__ rowmin, unsigned* __restrict__ colmin) {
    __shared__ __align__(16) unsigned char sA[32768];
    __shared__ __align__(16) unsigned char sB[32768];

    const int t = threadIdx.x;
    const int tile_m = blockIdx.y * 128;
    const int tile_n = blockIdx.x * 128;

    // ---- stage A and B panels (128 rows x 128 k, bf16) ----
    #pragma unroll
    for (int it = 0; it < 8; ++it) {
        int c  = it * 256 + t;           // chunk 0..2047
        int r  = c >> 4;                 // row in tile 0..127
        int kc = c & 15;                 // 8-element k-chunk 0..15
        int lds_off = r * 256 + ((kc * 16) ^ ((r & 7) << 4));
        {
            const float4* p = reinterpret_cast<const float4*>(&A[(size_t)(tile_m + r) * DIM + kc * 8]);
            float4 u = p[0], v = p[1];
            bf16x8 w;
            w[0]=(__bf16)u.x; w[1]=(__bf16)u.y; w[2]=(__bf16)u.z; w[3]=(__bf16)u.w;
            w[4]=(__bf16)v.x; w[5]=(__bf16)v.y; w[6]=(__bf16)v.z; w[7]=(__bf16)v.w;
            *reinterpret_cast<bf16x8*>(&sA[lds_off]) = w;
        }
        {
            const float4* p = reinterpret_cast<const float4*>(&B[(size_t)(tile_n + r) * DIM + kc * 8]);
            float4 u = p[0], v = p[1];
            bf16x8 w;
            w[0]=(__bf16)u.x; w[1]=(__bf16)u.y; w[2]=(__bf16)u.z; w[3]=(__bf16)u.w;
            w[4]=(__bf16)v.x; w[5]=(__bf16)v.y; w[6]=(__bf16)v.z; w[7]=(__bf16)v.w;
            *reinterpret_cast<bf16x8*>(&sB[lds_off]) = w;
        }
    }
    __syncthreads();

    const int w  = t >> 6, lane = t & 63;
    const int wr = (w >> 1) * 64;   // wave's m-offset in tile
    const int wc = (w & 1) * 64;    // wave's n-offset in tile
    const int lq = lane >> 4, lr = lane & 15;

    f32x4 acc[4][4] = {};
    #pragma unroll
    for (int ks = 0; ks < 4; ++ks) {
        const int kc = ks * 4 + lq;
        bf16x8 af[4], bfr[4];
        #pragma unroll
        for (int mi = 0; mi < 4; ++mi) {
            int r = wr + mi * 16 + lr;
            af[mi] = *reinterpret_cast<const bf16x8*>(&sA[r * 256 + ((kc * 16) ^ ((r & 7) << 4))]);
        }
        #pragma unroll
        for (int ni = 0; ni < 4; ++ni) {
            int r = wc + ni * 16 + lr;
            bfr[ni] = *reinterpret_cast<const bf16x8*>(&sB[r * 256 + ((kc * 16) ^ ((r & 7) << 4))]);
        }
        #pragma unroll
        for (int mi = 0; mi < 4; ++mi)
            #pragma unroll
            for (int ni = 0; ni < 4; ++ni)
                acc[mi][ni] = __builtin_amdgcn_mfma_f32_16x16x32_bf16(af[mi], bfr[ni], acc[mi][ni], 0, 0, 0);
    }

    // ---- epilogue: dist = a2[r] + b2[c] - 2*ab; row & col minima ----
    // C/D layout per frag: col = lr, row = lq*4 + j.
    float b2v[4];
    #pragma unroll
    for (int ni = 0; ni < 4; ++ni) b2v[ni] = b2[tile_n + wc + ni * 16 + lr];
    float a2v[4][4];
    #pragma unroll
    for (int mi = 0; mi < 4; ++mi)
        #pragma unroll
        for (int j = 0; j < 4; ++j) a2v[mi][j] = a2[tile_m + wr + mi * 16 + lq * 4 + j];

    // row minima over this wave's 64 columns
    float rmin[4][4];
    #pragma unroll
    for (int mi = 0; mi < 4; ++mi) {
        #pragma unroll
        for (int j = 0; j < 4; ++j) {
            float m0 = fminf(fmaf(-2.f, acc[mi][0][j], b2v[0]), fmaf(-2.f, acc[mi][1][j], b2v[1]));
            float m1 = fminf(fmaf(-2.f, acc[mi][2][j], b2v[2]), fmaf(-2.f, acc[mi][3][j], b2v[3]));
            float m  = fminf(m0, m1);
            #pragma unroll
            for (int off = 1; off < 16; off <<= 1) m = fminf(m, __shfl_xor(m, off));
            rmin[mi][j] = m + a2v[mi][j];
        }
    }

    // col minima over this wave's 64 rows
    float cmin[4];
    #pragma unroll
    for (int ni = 0; ni < 4; ++ni) {
        float m = fmaf(-2.f, acc[0][ni][0], a2v[0][0]);
        #pragma unroll
        for (int mi = 0; mi < 4; ++mi)
            #pragma unroll
            for (int j = 0; j < 4; ++j)
                if (mi | j) m = fminf(m, fmaf(-2.f, acc[mi][ni][j], a2v[mi][j]));
        m = fminf(m, __shfl_xor(m, 16));
        m = fminf(m, __shfl_xor(m, 32));
        cmin[ni] = m + b2v[ni];
    }

    // ---- block-level min combine in LDS (reuse sA), then one global atomic per row/col ----
    __syncthreads();                       // all waves done reading sA
    unsigned* rmin_s = reinterpret_cast<unsigned*>(sA);
    unsigned* cmin_s = rmin_s + 128;
    reinterpret_cast<unsigned*>(sA)[t < 256 ? t : 0] = 0xFFFFFFFFu;  // t in [0,256): init both arrays
    __syncthreads();

    if (lr == 0) {
        #pragma unroll
        for (int mi = 0; mi < 4; ++mi)
            #pragma unroll
            for (int j = 0; j < 4; ++j)
                atomicMin(&rmin_s[wr + mi * 16 + lq * 4 + j], fmap(rmin[mi][j]));
    }
    if (lq == 0) {
        #pragma unroll
        for (int ni = 0; ni < 4; ++ni)
            atomicMin(&cmin_s[wc + ni * 16 + lr], fmap(cmin[ni]));
    }
    __syncthreads();

    if (t < 128) atomicMin(&rowmin[tile_m + t], rmin_s[t]);
    else         atomicMin(&colmin[tile_n + t - 128], cmin_s[t - 128]);
}

// ---------------------------------------------------------------------------
// Kernel 3: sum the 2*N minima (double accumulation) -> scalar mean sum.
// ---------------------------------------------------------------------------
__global__ void chamfer_finalize(const unsigned* __restrict__ rowmin,
                                 const unsigned* __restrict__ colmin,
                                 float* __restrict__ out) {
    __shared__ double sred[4];
    int t = threadIdx.x;
    double s = 0.0;
    for (int i = t; i < N_PTS; i += 256)
        s += (double)funmap(rowmin[i]) + (double)funmap(colmin[i]);
    #pragma unroll
    for (int off = 32; off; off >>= 1) s += __shfl_down(s, off);
    if ((t & 63) == 0) sred[t >> 6] = s;
    __syncthreads();
    if (t == 0) out[0] = (float)((sred[0] + sred[1] + sred[2] + sred[3]) * (1.0 / (double)N_PTS));
}

// ---------------------------------------------------------------------------
extern "C" void kernel_launch(void* const* d_in, const int* in_sizes, int n_in,
                              void* d_out, int out_size, void* d_ws, size_t ws_size,
                              hipStream_t stream) {
    const float* A = (const float*)d_in[0];
    const float* B = (const float*)d_in[1];
    float* out = (float*)d_out;

    char* ws = (char*)d_ws;                       // needs 256 KB total
    float*    a2     = (float*)(ws);              // 64 KB
    float*    b2     = (float*)(ws + (1 << 16));  // 64 KB
    unsigned* rowmin = (unsigned*)(ws + (2 << 16));
    unsigned* colmin = (unsigned*)(ws + (3 << 16));

    chamfer_prep<<<(2 * N_PTS) / 4, 256, 0, stream>>>(A, B, a2, b2, rowmin, colmin);

    dim3 grid(N_PTS / 128, N_PTS / 128);
    chamfer_gemm_min<<<grid, 256, 0, stream>>>(A, B, a2, b2, rowmin, colmin);

    chamfer_finalize<<<1, 256, 0, stream>>>(rowmin, colmin, out);
}

// Round 2
// 178.089 us; speedup vs baseline: 1.1516x; 1.1516x over previous
//
#include <hip/hip_runtime.h>
#include <hip/hip_bf16.h>

#define N_PTS 16384
#define DIM   128

typedef __bf16 bf16x8 __attribute__((ext_vector_type(8)));
typedef float  f32x4  __attribute__((ext_vector_type(4)));

// Monotone map float -> uint so unsigned atomicMin == float min (handles negatives).
__device__ __forceinline__ unsigned fmap(float f) {
    unsigned u = __float_as_uint(f);
    return (u & 0x80000000u) ? ~u : (u | 0x80000000u);
}
__device__ __forceinline__ float funmap(unsigned u) {
    return __uint_as_float((u & 0x80000000u) ? (u & 0x7FFFFFFFu) : ~u);
}

// Async global->LDS, 16B per lane. LDS dest is wave-uniform base + lane*16 (linear);
// swizzled layout is achieved by pre-swizzling the per-lane GLOBAL source address.
__device__ __forceinline__ void gload_lds16(const void* g, void* l) {
    __builtin_amdgcn_global_load_lds(
        (const __attribute__((address_space(1))) void*)g,
        (__attribute__((address_space(3))) void*)l, 16, 0, 0);
}

// ---------------------------------------------------------------------------
// Fast-path prep: one wave per row. Computes fp32 row norm, converts the row
// to bf16 (RNE, identical numerics to round-1 in-kernel conversion), inits
// the global min arrays. Rows 0..N-1 = cloud1, N..2N-1 = cloud2.
// ---------------------------------------------------------------------------
__global__ void chamfer_prep2(const float* __restrict__ A, const float* __restrict__ B,
                              unsigned short* __restrict__ Abf, unsigned short* __restrict__ Bbf,
                              float* __restrict__ a2, float* __restrict__ b2,
                              unsigned* __restrict__ rowmin, unsigned* __restrict__ colmin) {
    int wave = blockIdx.x * 4 + (threadIdx.x >> 6);
    int lane = threadIdx.x & 63;
    int isB  = wave >= N_PTS;
    int row  = isB ? (wave - N_PTS) : wave;
    const float* src = isB ? B : A;
    unsigned short* dst = isB ? Bbf : Abf;

    float2 v = *reinterpret_cast<const float2*>(&src[(size_t)row * DIM + lane * 2]);

    __bf16 bx = (__bf16)v.x, by = (__bf16)v.y;
    ushort2 st;
    st.x = __builtin_bit_cast(unsigned short, bx);
    st.y = __builtin_bit_cast(unsigned short, by);
    *reinterpret_cast<ushort2*>(&dst[(size_t)row * DIM + lane * 2]) = st;

    float s = fmaf(v.x, v.x, v.y * v.y);
    #pragma unroll
    for (int off = 32; off; off >>= 1) s += __shfl_down(s, off);
    if (lane == 0) {
        if (isB) { b2[row] = s; colmin[row] = 0xFFFFFFFFu; }
        else     { a2[row] = s; rowmin[row] = 0xFFFFFFFFu; }
    }
}

// ---------------------------------------------------------------------------
// Fast-path GEMM+min: 128x128 tile, 4 waves, bf16 panels staged from global
// via global_load_lds (zero staging VALU). LDS layout XOR-swizzled
// (byte = r*256 + ((kc*16) ^ ((r&7)<<4))) via pre-swizzled global source.
// XCD-aware remap: XCD x owns tile-rows [x*16, x*16+16), walked column-major
// so each B panel is reused by 16 consecutive blocks on that XCD.
// ---------------------------------------------------------------------------
__global__ __launch_bounds__(256, 2)
void chamfer_gemm_min2(const unsigned short* __restrict__ Abf, const unsigned short* __restrict__ Bbf,
                       const float* __restrict__ a2, const float* __restrict__ b2,
                       unsigned* __restrict__ rowmin, unsigned* __restrict__ colmin) {
    __shared__ __align__(16) unsigned char sA[32768];
    __shared__ __align__(16) unsigned char sB[32768];

    const int lin = blockIdx.x;          // 16384 blocks
    const int xcd = lin & 7;
    const int tt  = lin >> 3;            // 0..2047 within XCD
    const int tile_m = ((xcd << 4) + (tt & 15)) << 7;   // 16-row band per XCD
    const int tile_n = (tt >> 4) << 7;                  // column-major walk

    const int t = threadIdx.x;
    const int w = t >> 6, lane = t & 63;

    // ---- stage A and B panels (128 rows x 128 k, bf16) ----
    #pragma unroll
    for (int j = 0; j < 8; ++j) {
        int chunk = ((w * 8 + j) << 6) | lane;   // 16B chunk index 0..2047
        int r   = chunk >> 4;                    // row in tile
        int kcp = chunk & 15;                    // swizzled k-chunk slot
        int kc  = kcp ^ (r & 7);                 // global k-chunk that belongs there
        gload_lds16(Abf + (size_t)(tile_m + r) * DIM + kc * 8, sA + (w * 8 + j) * 1024);
        gload_lds16(Bbf + (size_t)(tile_n + r) * DIM + kc * 8, sB + (w * 8 + j) * 1024);
    }
    __syncthreads();   // compiler drains vmcnt before s_barrier

    const int wr = (w >> 1) * 64;   // wave's m-offset in tile
    const int wc = (w & 1) * 64;    // wave's n-offset in tile
    const int lq = lane >> 4, lr = lane & 15;

    f32x4 acc[4][4] = {};
    #pragma unroll
    for (int ks = 0; ks < 4; ++ks) {
        const int kc = ks * 4 + lq;
        bf16x8 af[4], bfr[4];
        #pragma unroll
        for (int mi = 0; mi < 4; ++mi) {
            int r = wr + mi * 16 + lr;
            af[mi] = *reinterpret_cast<const bf16x8*>(&sA[r * 256 + ((kc * 16) ^ ((r & 7) << 4))]);
        }
        #pragma unroll
        for (int ni = 0; ni < 4; ++ni) {
            int r = wc + ni * 16 + lr;
            bfr[ni] = *reinterpret_cast<const bf16x8*>(&sB[r * 256 + ((kc * 16) ^ ((r & 7) << 4))]);
        }
        #pragma unroll
        for (int mi = 0; mi < 4; ++mi)
            #pragma unroll
            for (int ni = 0; ni < 4; ++ni)
                acc[mi][ni] = __builtin_amdgcn_mfma_f32_16x16x32_bf16(af[mi], bfr[ni], acc[mi][ni], 0, 0, 0);
    }

    // ---- epilogue: dist = a2[r] + b2[c] - 2*ab; row & col minima ----
    // C/D layout per frag: col = lr, row = lq*4 + j.
    float b2v[4];
    #pragma unroll
    for (int ni = 0; ni < 4; ++ni) b2v[ni] = b2[tile_n + wc + ni * 16 + lr];
    float a2v[4][4];
    #pragma unroll
    for (int mi = 0; mi < 4; ++mi)
        #pragma unroll
        for (int j = 0; j < 4; ++j) a2v[mi][j] = a2[tile_m + wr + mi * 16 + lq * 4 + j];

    float rmin[4][4];
    #pragma unroll
    for (int mi = 0; mi < 4; ++mi) {
        #pragma unroll
        for (int j = 0; j < 4; ++j) {
            float m0 = fminf(fmaf(-2.f, acc[mi][0][j], b2v[0]), fmaf(-2.f, acc[mi][1][j], b2v[1]));
            float m1 = fminf(fmaf(-2.f, acc[mi][2][j], b2v[2]), fmaf(-2.f, acc[mi][3][j], b2v[3]));
            float m  = fminf(m0, m1);
            #pragma unroll
            for (int off = 1; off < 16; off <<= 1) m = fminf(m, __shfl_xor(m, off));
            rmin[mi][j] = m + a2v[mi][j];
        }
    }

    float cmin[4];
    #pragma unroll
    for (int ni = 0; ni < 4; ++ni) {
        float m = fmaf(-2.f, acc[0][ni][0], a2v[0][0]);
        #pragma unroll
        for (int mi = 0; mi < 4; ++mi)
            #pragma unroll
            for (int j = 0; j < 4; ++j)
                if (mi | j) m = fminf(m, fmaf(-2.f, acc[mi][ni][j], a2v[mi][j]));
        m = fminf(m, __shfl_xor(m, 16));
        m = fminf(m, __shfl_xor(m, 32));
        cmin[ni] = m + b2v[ni];
    }

    // ---- block-level min combine in LDS (reuse sA), then one global atomic per row/col ----
    __syncthreads();
    unsigned* rmin_s = reinterpret_cast<unsigned*>(sA);
    unsigned* cmin_s = rmin_s + 128;
    reinterpret_cast<unsigned*>(sA)[t] = 0xFFFFFFFFu;   // t in [0,256): covers both arrays
    __syncthreads();

    if (lr == 0) {
        #pragma unroll
        for (int mi = 0; mi < 4; ++mi)
            #pragma unroll
            for (int j = 0; j < 4; ++j)
                atomicMin(&rmin_s[wr + mi * 16 + lq * 4 + j], fmap(rmin[mi][j]));
    }
    if (lq == 0) {
        #pragma unroll
        for (int ni = 0; ni < 4; ++ni)
            atomicMin(&cmin_s[wc + ni * 16 + lr], fmap(cmin[ni]));
    }
    __syncthreads();

    if (t < 128) atomicMin(&rowmin[tile_m + t], rmin_s[t]);
    else         atomicMin(&colmin[tile_n + t - 128], cmin_s[t - 128]);
}

// ---------------------------------------------------------------------------
// Fallback path (round-1, known-passing): used only if ws_size is too small
// for the bf16 copies.
// ---------------------------------------------------------------------------
__global__ void chamfer_prep_fb(const float* __restrict__ A, const float* __restrict__ B,
                                float* __restrict__ a2, float* __restrict__ b2,
                                unsigned* __restrict__ rowmin, unsigned* __restrict__ colmin) {
    int wave = blockIdx.x * 4 + (threadIdx.x >> 6);
    int lane = threadIdx.x & 63;
    int isB  = wave >= N_PTS;
    int row  = isB ? (wave - N_PTS) : wave;
    const float* src = isB ? B : A;
    float2 v = *reinterpret_cast<const float2*>(&src[(size_t)row * DIM + lane * 2]);
    float s = v.x * v.x + v.y * v.y;
    #pragma unroll
    for (int off = 32; off; off >>= 1) s += __shfl_down(s, off);
    if (lane == 0) {
        if (isB) { b2[row] = s; colmin[row] = 0xFFFFFFFFu; }
        else     { a2[row] = s; rowmin[row] = 0xFFFFFFFFu; }
    }
}

__global__ __launch_bounds__(256, 2)
void chamfer_gemm_min_fb(const float* __restrict__ A, const float* __restrict__ B,
                         const float* __restrict__ a2, const float* __restrict__ b2,
                         unsigned* __restrict__ rowmin, unsigned* __restrict__ colmin) {
    __shared__ __align__(16) unsigned char sA[32768];
    __shared__ __align__(16) unsigned char sB[32768];

    const int t = threadIdx.x;
    const int tile_m = blockIdx.y * 128;
    const int tile_n = blockIdx.x * 128;

    #pragma unroll
    for (int it = 0; it < 8; ++it) {
        int c  = it * 256 + t;
        int r  = c >> 4;
        int kc = c & 15;
        int lds_off = r * 256 + ((kc * 16) ^ ((r & 7) << 4));
        {
            const float4* p = reinterpret_cast<const float4*>(&A[(size_t)(tile_m + r) * DIM + kc * 8]);
            float4 u = p[0], v = p[1];
            bf16x8 wv;
            wv[0]=(__bf16)u.x; wv[1]=(__bf16)u.y; wv[2]=(__bf16)u.z; wv[3]=(__bf16)u.w;
            wv[4]=(__bf16)v.x; wv[5]=(__bf16)v.y; wv[6]=(__bf16)v.z; wv[7]=(__bf16)v.w;
            *reinterpret_cast<bf16x8*>(&sA[lds_off]) = wv;
        }
        {
            const float4* p = reinterpret_cast<const float4*>(&B[(size_t)(tile_n + r) * DIM + kc * 8]);
            float4 u = p[0], v = p[1];
            bf16x8 wv;
            wv[0]=(__bf16)u.x; wv[1]=(__bf16)u.y; wv[2]=(__bf16)u.z; wv[3]=(__bf16)u.w;
            wv[4]=(__bf16)v.x; wv[5]=(__bf16)v.y; wv[6]=(__bf16)v.z; wv[7]=(__bf16)v.w;
            *reinterpret_cast<bf16x8*>(&sB[lds_off]) = wv;
        }
    }
    __syncthreads();

    const int w  = t >> 6, lane = t & 63;
    const int wr = (w >> 1) * 64;
    const int wc = (w & 1) * 64;
    const int lq = lane >> 4, lr = lane & 15;

    f32x4 acc[4][4] = {};
    #pragma unroll
    for (int ks = 0; ks < 4; ++ks) {
        const int kc = ks * 4 + lq;
        bf16x8 af[4], bfr[4];
        #pragma unroll
        for (int mi = 0; mi < 4; ++mi) {
            int r = wr + mi * 16 + lr;
            af[mi] = *reinterpret_cast<const bf16x8*>(&sA[r * 256 + ((kc * 16) ^ ((r & 7) << 4))]);
        }
        #pragma unroll
        for (int ni = 0; ni < 4; ++ni) {
            int r = wc + ni * 16 + lr;
            bfr[ni] = *reinterpret_cast<const bf16x8*>(&sB[r * 256 + ((kc * 16) ^ ((r & 7) << 4))]);
        }
        #pragma unroll
        for (int mi = 0; mi < 4; ++mi)
            #pragma unroll
            for (int ni = 0; ni < 4; ++ni)
                acc[mi][ni] = __builtin_amdgcn_mfma_f32_16x16x32_bf16(af[mi], bfr[ni], acc[mi][ni], 0, 0, 0);
    }

    float b2v[4];
    #pragma unroll
    for (int ni = 0; ni < 4; ++ni) b2v[ni] = b2[tile_n + wc + ni * 16 + lr];
    float a2v[4][4];
    #pragma unroll
    for (int mi = 0; mi < 4; ++mi)
        #pragma unroll
        for (int j = 0; j < 4; ++j) a2v[mi][j] = a2[tile_m + wr + mi * 16 + lq * 4 + j];

    float rmin[4][4];
    #pragma unroll
    for (int mi = 0; mi < 4; ++mi) {
        #pragma unroll
        for (int j = 0; j < 4; ++j) {
            float m0 = fminf(fmaf(-2.f, acc[mi][0][j], b2v[0]), fmaf(-2.f, acc[mi][1][j], b2v[1]));
            float m1 = fminf(fmaf(-2.f, acc[mi][2][j], b2v[2]), fmaf(-2.f, acc[mi][3][j], b2v[3]));
            float m  = fminf(m0, m1);
            #pragma unroll
            for (int off = 1; off < 16; off <<= 1) m = fminf(m, __shfl_xor(m, off));
            rmin[mi][j] = m + a2v[mi][j];
        }
    }

    float cmin[4];
    #pragma unroll
    for (int ni = 0; ni < 4; ++ni) {
        float m = fmaf(-2.f, acc[0][ni][0], a2v[0][0]);
        #pragma unroll
        for (int mi = 0; mi < 4; ++mi)
            #pragma unroll
            for (int j = 0; j < 4; ++j)
                if (mi | j) m = fminf(m, fmaf(-2.f, acc[mi][ni][j], a2v[mi][j]));
        m = fminf(m, __shfl_xor(m, 16));
        m = fminf(m, __shfl_xor(m, 32));
        cmin[ni] = m + b2v[ni];
    }

    __syncthreads();
    unsigned* rmin_s = reinterpret_cast<unsigned*>(sA);
    unsigned* cmin_s = rmin_s + 128;
    reinterpret_cast<unsigned*>(sA)[t] = 0xFFFFFFFFu;
    __syncthreads();

    if (lr == 0) {
        #pragma unroll
        for (int mi = 0; mi < 4; ++mi)
            #pragma unroll
            for (int j = 0; j < 4; ++j)
                atomicMin(&rmin_s[wr + mi * 16 + lq * 4 + j], fmap(rmin[mi][j]));
    }
    if (lq == 0) {
        #pragma unroll
        for (int ni = 0; ni < 4; ++ni)
            atomicMin(&cmin_s[wc + ni * 16 + lr], fmap(cmin[ni]));
    }
    __syncthreads();

    if (t < 128) atomicMin(&rowmin[tile_m + t], rmin_s[t]);
    else         atomicMin(&colmin[tile_n + t - 128], cmin_s[t - 128]);
}

// ---------------------------------------------------------------------------
// Final reduction: sum 2*N minima in double -> mean sum. 1024 threads.
// ---------------------------------------------------------------------------
__global__ void chamfer_finalize(const unsigned* __restrict__ rowmin,
                                 const unsigned* __restrict__ colmin,
                                 float* __restrict__ out) {
    __shared__ double sred[16];
    int t = threadIdx.x;
    double s = 0.0;
    for (int i = t; i < N_PTS; i += 1024)
        s += (double)funmap(rowmin[i]) + (double)funmap(colmin[i]);
    #pragma unroll
    for (int off = 32; off; off >>= 1) s += __shfl_down(s, off);
    if ((t & 63) == 0) sred[t >> 6] = s;
    __syncthreads();
    if (t == 0) {
        double tot = 0.0;
        #pragma unroll
        for (int i = 0; i < 16; ++i) tot += sred[i];
        out[0] = (float)(tot * (1.0 / (double)N_PTS));
    }
}

// ---------------------------------------------------------------------------
extern "C" void kernel_launch(void* const* d_in, const int* in_sizes, int n_in,
                              void* d_out, int out_size, void* d_ws, size_t ws_size,
                              hipStream_t stream) {
    const float* A = (const float*)d_in[0];
    const float* B = (const float*)d_in[1];
    float* out = (float*)d_out;
    char* ws = (char*)d_ws;

    const size_t BF = (size_t)N_PTS * DIM * sizeof(unsigned short);  // 4 MB per cloud
    const size_t need = 2 * BF + 4 * (size_t)N_PTS * 4;              // + a2,b2,rowmin,colmin

    if (ws_size >= need) {
        unsigned short* Abf = (unsigned short*)(ws);
        unsigned short* Bbf = (unsigned short*)(ws + BF);
        float*    a2     = (float*)(ws + 2 * BF);
        float*    b2     = (float*)(ws + 2 * BF + (1 << 16));
        unsigned* rowmin = (unsigned*)(ws + 2 * BF + (2 << 16));
        unsigned* colmin = (unsigned*)(ws + 2 * BF + (3 << 16));

        chamfer_prep2<<<(2 * N_PTS) / 4, 256, 0, stream>>>(A, B, Abf, Bbf, a2, b2, rowmin, colmin);
        chamfer_gemm_min2<<<16384, 256, 0, stream>>>(Abf, Bbf, a2, b2, rowmin, colmin);
        chamfer_finalize<<<1, 1024, 0, stream>>>(rowmin, colmin, out);
    } else {
        float*    a2     = (float*)(ws);
        float*    b2     = (float*)(ws + (1 << 16));
        unsigned* rowmin = (unsigned*)(ws + (2 << 16));
        unsigned* colmin = (unsigned*)(ws + (3 << 16));

        chamfer_prep_fb<<<(2 * N_PTS) / 4, 256, 0, stream>>>(A, B, a2, b2, rowmin, colmin);
        dim3 grid(N_PTS / 128, N_PTS / 128);
        chamfer_gemm_min_fb<<<grid, 256, 0, stream>>>(A, B, a2, b2, rowmin, colmin);
        chamfer_finalize<<<1, 1024, 0, stream>>>(rowmin, colmin, out);
    }
}

// Round 3
// 119.638 us; speedup vs baseline: 1.7143x; 1.4886x over previous
//
#include <hip/hip_runtime.h>
#include <hip/hip_bf16.h>

#define N_PTS 16384
#define DIM   128

typedef __bf16 bf16x8 __attribute__((ext_vector_type(8)));
typedef float  f32x4  __attribute__((ext_vector_type(4)));

// Monotone map float -> uint so unsigned atomicMin == float min (handles negatives).
__device__ __forceinline__ unsigned fmap(float f) {
    unsigned u = __float_as_uint(f);
    return (u & 0x80000000u) ? ~u : (u | 0x80000000u);
}
__device__ __forceinline__ float funmap(unsigned u) {
    return __uint_as_float((u & 0x80000000u) ? (u & 0x7FFFFFFFu) : ~u);
}

// Async global->LDS, 16B per lane. LDS dest linear (base + lane*16); swizzled
// layout achieved by pre-swizzling the per-lane GLOBAL source address.
__device__ __forceinline__ void gload_lds16(const void* g, void* l) {
    __builtin_amdgcn_global_load_lds(
        (const __attribute__((address_space(1))) void*)g,
        (__attribute__((address_space(3))) void*)l, 16, 0, 0);
}

// ---------------------------------------------------------------------------
// Prep: one wave per row. fp32 row norm, bf16 copy of the row, init min arrays.
// ---------------------------------------------------------------------------
__global__ void chamfer_prep2(const float* __restrict__ A, const float* __restrict__ B,
                              unsigned short* __restrict__ Abf, unsigned short* __restrict__ Bbf,
                              float* __restrict__ a2, float* __restrict__ b2,
                              unsigned* __restrict__ rowmin, unsigned* __restrict__ colmin) {
    int wave = blockIdx.x * 4 + (threadIdx.x >> 6);
    int lane = threadIdx.x & 63;
    int isB  = wave >= N_PTS;
    int row  = isB ? (wave - N_PTS) : wave;
    const float* src = isB ? B : A;
    unsigned short* dst = isB ? Bbf : Abf;

    float2 v = *reinterpret_cast<const float2*>(&src[(size_t)row * DIM + lane * 2]);

    __bf16 bx = (__bf16)v.x, by = (__bf16)v.y;
    ushort2 st;
    st.x = __builtin_bit_cast(unsigned short, bx);
    st.y = __builtin_bit_cast(unsigned short, by);
    *reinterpret_cast<ushort2*>(&dst[(size_t)row * DIM + lane * 2]) = st;

    float s = fmaf(v.x, v.x, v.y * v.y);
    #pragma unroll
    for (int off = 32; off; off >>= 1) s += __shfl_down(s, off);
    if (lane == 0) {
        if (isB) { b2[row] = s; colmin[row] = 0xFFFFFFFFu; }
        else     { a2[row] = s; rowmin[row] = 0xFFFFFFFFu; }
    }
}

// ---------------------------------------------------------------------------
// Persistent GEMM+min. 256 blocks x 512 threads (8 waves, 4x2 wave grid).
// Block b: A rows [ (b>>2)*256, +256 ) pinned in LDS; walks 32 B-tiles of 128
// cols: tn = (b&3)*32 + it. B double-buffered, prefetched at iteration top.
// rowmin accumulates min_c(b2[c]-2ab); colmin accumulates min_r(a2[r]-2ab);
// a2/b2 re-added in finalize.
// ---------------------------------------------------------------------------
__global__ __launch_bounds__(512, 2)
void chamfer_gemm_min3(const unsigned short* __restrict__ Abf, const unsigned short* __restrict__ Bbf,
                       const float* __restrict__ a2, const float* __restrict__ b2,
                       unsigned* __restrict__ rowmin, unsigned* __restrict__ colmin) {
    __shared__ __align__(16) unsigned char sA[65536];
    __shared__ __align__(16) unsigned char sB[2][32768];

    const int b = blockIdx.x;
    const int tm_base = (b >> 2) * 256;
    const int tn0 = (b & 3) * 32;

    const int t = threadIdx.x;
    const int w = t >> 6, lane = t & 63;
    const int lq = lane >> 4, lr = lane & 15;
    const int wr = (w >> 1) * 64;   // m-offset in 256-row panel
    const int wc = (w & 1) * 64;    // n-offset in 128-col tile

    // ---- prologue: stage A (256x128 bf16 = 64KB) + first B (32KB) ----
    #pragma unroll
    for (int j = 0; j < 8; ++j) {
        int chunk = ((w << 3) + j) * 64 + lane;            // [0,4096)
        int r = chunk >> 4, kc = (chunk & 15) ^ (r & 7);
        gload_lds16(Abf + (size_t)(tm_base + r) * DIM + kc * 8, sA + chunk * 16);
    }
    #pragma unroll
    for (int j = 0; j < 4; ++j) {
        int chunk = ((w << 2) + j) * 64 + lane;            // [0,2048)
        int r = chunk >> 4, kc = (chunk & 15) ^ (r & 7);
        gload_lds16(Bbf + (size_t)(tn0 * 128 + r) * DIM + kc * 8, sB[0] + chunk * 16);
    }

    // a2 fragment values for this wave's rows (constant across iterations)
    float a2v[4][4];
    #pragma unroll
    for (int mi = 0; mi < 4; ++mi) {
        float4 q = *reinterpret_cast<const float4*>(&a2[tm_base + wr + mi * 16 + lq * 4]);
        a2v[mi][0] = q.x; a2v[mi][1] = q.y; a2v[mi][2] = q.z; a2v[mi][3] = q.w;
    }

    __syncthreads();

    for (int it = 0; it < 32; ++it) {
        const int cur = it & 1;
        const int tn = tn0 + it;

        // prefetch next B tile into the other buffer (overlaps with compute)
        if (it + 1 < 32) {
            #pragma unroll
            for (int j = 0; j < 4; ++j) {
                int chunk = ((w << 2) + j) * 64 + lane;
                int r = chunk >> 4, kc = (chunk & 15) ^ (r & 7);
                gload_lds16(Bbf + (size_t)((tn + 1) * 128 + r) * DIM + kc * 8,
                            sB[cur ^ 1] + chunk * 16);
            }
        }

        // ---- MFMA: 64x64 per wave, K=128 in 4 k-steps ----
        f32x4 acc[4][4] = {};
        #pragma unroll
        for (int ks = 0; ks < 4; ++ks) {
            const int kc = ks * 4 + lq;
            bf16x8 af[4], bfr[4];
            #pragma unroll
            for (int mi = 0; mi < 4; ++mi) {
                int r = wr + mi * 16 + lr;
                af[mi] = *reinterpret_cast<const bf16x8*>(&sA[r * 256 + ((kc * 16) ^ ((r & 7) << 4))]);
            }
            #pragma unroll
            for (int ni = 0; ni < 4; ++ni) {
                int r = wc + ni * 16 + lr;
                bfr[ni] = *reinterpret_cast<const bf16x8*>(&sB[cur][r * 256 + ((kc * 16) ^ ((r & 7) << 4))]);
            }
            #pragma unroll
            for (int mi = 0; mi < 4; ++mi)
                #pragma unroll
                for (int ni = 0; ni < 4; ++ni)
                    acc[mi][ni] = __builtin_amdgcn_mfma_f32_16x16x32_bf16(af[mi], bfr[ni], acc[mi][ni], 0, 0, 0);
        }

        // ---- epilogue ----
        // C/D layout: row = wr + mi*16 + lq*4 + j, col = wc + ni*16 + lr.
        const int col_base = tn * 128 + wc;
        float b2v[4];
        #pragma unroll
        for (int ni = 0; ni < 4; ++ni) b2v[ni] = b2[col_base + ni * 16 + lr];

        // Row path: v[mi*4+j] = min over this wave's 64 cols of (b2[c] - 2ab)
        float v[16];
        #pragma unroll
        for (int mi = 0; mi < 4; ++mi) {
            #pragma unroll
            for (int j = 0; j < 4; ++j) {
                float m = fmaf(-2.f, acc[mi][0][j], b2v[0]);
                m = fminf(m, fmaf(-2.f, acc[mi][1][j], b2v[1]));
                m = fminf(m, fmaf(-2.f, acc[mi][2][j], b2v[2]));
                m = fminf(m, fmaf(-2.f, acc[mi][3][j], b2v[3]));
                v[mi * 4 + j] = m;
            }
        }
        // Reduce-scatter 16 vars over the 16 lr lanes: after 4 stages lane lr
        // owns var lr (var = mi*4+j), fully min-reduced over lr.
        #pragma unroll
        for (int k = 0; k < 8; ++k) {
            float s = (lr & 8) ? v[k] : v[k + 8];
            float r = __shfl_xor(s, 8);
            v[k] = (lr & 8) ? fminf(v[k + 8], r) : fminf(v[k], r);
        }
        #pragma unroll
        for (int k = 0; k < 4; ++k) {
            float s = (lr & 4) ? v[k] : v[k + 4];
            float r = __shfl_xor(s, 4);
            v[k] = (lr & 4) ? fminf(v[k + 4], r) : fminf(v[k], r);
        }
        #pragma unroll
        for (int k = 0; k < 2; ++k) {
            float s = (lr & 2) ? v[k] : v[k + 2];
            float r = __shfl_xor(s, 2);
            v[k] = (lr & 2) ? fminf(v[k + 2], r) : fminf(v[k], r);
        }
        {
            float s = (lr & 1) ? v[0] : v[1];
            float r = __shfl_xor(s, 1);
            v[0] = (lr & 1) ? fminf(v[1], r) : fminf(v[0], r);
        }
        const int own_row = tm_base + wr + ((lr >> 2) << 4) + (lq << 2) + (lr & 3);

        // Col path: cp[ni] = min over this wave's 64 rows of (a2[r] - 2ab)
        float cp[4];
        #pragma unroll
        for (int ni = 0; ni < 4; ++ni) {
            float m = fmaf(-2.f, acc[0][ni][0], a2v[0][0]);
            #pragma unroll
            for (int mi = 0; mi < 4; ++mi)
                #pragma unroll
                for (int j = 0; j < 4; ++j)
                    if (mi | j) m = fminf(m, fmaf(-2.f, acc[mi][ni][j], a2v[mi][j]));
            cp[ni] = m;
        }
        // Reduce-scatter 4 vars over the 4 lq groups (xor 16, xor 32):
        // lane ends owning ni = ((lq&1)<<1) | (lq>>1).
        #pragma unroll
        for (int k = 0; k < 2; ++k) {
            float s = (lane & 16) ? cp[k] : cp[k + 2];
            float r = __shfl_xor(s, 16);
            cp[k] = (lane & 16) ? fminf(cp[k + 2], r) : fminf(cp[k], r);
        }
        float cfin;
        {
            float s = (lane & 32) ? cp[0] : cp[1];
            float r = __shfl_xor(s, 32);
            cfin = (lane & 32) ? fminf(cp[1], r) : fminf(cp[0], r);
        }
        const int ni_own = ((lq & 1) << 1) | (lq >> 1);
        const int own_col = col_base + ni_own * 16 + lr;

        __syncthreads();   // next B landed (vmcnt drain); all waves done with sB[cur]

        // fire atomics after the barrier so their latency hides under next tile
        atomicMin(&rowmin[own_row], fmap(v[0]));
        atomicMin(&colmin[own_col], fmap(cfin));
    }
}

// ---------------------------------------------------------------------------
// Finalize (fast path): mean( a2[r] + rowmin_v[r] ) + mean( b2[c] + colmin_v[c] )
// ---------------------------------------------------------------------------
__global__ void chamfer_finalize2(const unsigned* __restrict__ rowmin,
                                  const unsigned* __restrict__ colmin,
                                  const float* __restrict__ a2, const float* __restrict__ b2,
                                  float* __restrict__ out) {
    __shared__ double sred[16];
    int t = threadIdx.x;
    double s = 0.0;
    for (int i = t; i < N_PTS; i += 1024)
        s += ((double)funmap(rowmin[i]) + (double)a2[i])
           + ((double)funmap(colmin[i]) + (double)b2[i]);
    #pragma unroll
    for (int off = 32; off; off >>= 1) s += __shfl_down(s, off);
    if ((t & 63) == 0) sred[t >> 6] = s;
    __syncthreads();
    if (t == 0) {
        double tot = 0.0;
        #pragma unroll
        for (int i = 0; i < 16; ++i) tot += sred[i];
        out[0] = (float)(tot * (1.0 / (double)N_PTS));
    }
}

// ---------------------------------------------------------------------------
// Fallback path (round-1, known-passing): only if ws_size too small.
// ---------------------------------------------------------------------------
__global__ void chamfer_prep_fb(const float* __restrict__ A, const float* __restrict__ B,
                                float* __restrict__ a2, float* __restrict__ b2,
                                unsigned* __restrict__ rowmin, unsigned* __restrict__ colmin) {
    int wave = blockIdx.x * 4 + (threadIdx.x >> 6);
    int lane = threadIdx.x & 63;
    int isB  = wave >= N_PTS;
    int row  = isB ? (wave - N_PTS) : wave;
    const float* src = isB ? B : A;
    float2 v = *reinterpret_cast<const float2*>(&src[(size_t)row * DIM + lane * 2]);
    float s = v.x * v.x + v.y * v.y;
    #pragma unroll
    for (int off = 32; off; off >>= 1) s += __shfl_down(s, off);
    if (lane == 0) {
        if (isB) { b2[row] = s; colmin[row] = 0xFFFFFFFFu; }
        else     { a2[row] = s; rowmin[row] = 0xFFFFFFFFu; }
    }
}

__global__ __launch_bounds__(256, 2)
void chamfer_gemm_min_fb(const float* __restrict__ A, const float* __restrict__ B,
                         const float* __restrict__ a2, const float* __restrict__ b2,
                         unsigned* __restrict__ rowmin, unsigned* __restrict__ colmin) {
    __shared__ __align__(16) unsigned char sA[32768];
    __shared__ __align__(16) unsigned char sB[32768];

    const int t = threadIdx.x;
    const int tile_m = blockIdx.y * 128;
    const int tile_n = blockIdx.x * 128;

    #pragma unroll
    for (int it = 0; it < 8; ++it) {
        int c  = it * 256 + t;
        int r  = c >> 4;
        int kc = c & 15;
        int lds_off = r * 256 + ((kc * 16) ^ ((r & 7) << 4));
        {
            const float4* p = reinterpret_cast<const float4*>(&A[(size_t)(tile_m + r) * DIM + kc * 8]);
            float4 u = p[0], vv = p[1];
            bf16x8 wv;
            wv[0]=(__bf16)u.x; wv[1]=(__bf16)u.y; wv[2]=(__bf16)u.z; wv[3]=(__bf16)u.w;
            wv[4]=(__bf16)vv.x; wv[5]=(__bf16)vv.y; wv[6]=(__bf16)vv.z; wv[7]=(__bf16)vv.w;
            *reinterpret_cast<bf16x8*>(&sA[lds_off]) = wv;
        }
        {
            const float4* p = reinterpret_cast<const float4*>(&B[(size_t)(tile_n + r) * DIM + kc * 8]);
            float4 u = p[0], vv = p[1];
            bf16x8 wv;
            wv[0]=(__bf16)u.x; wv[1]=(__bf16)u.y; wv[2]=(__bf16)u.z; wv[3]=(__bf16)u.w;
            wv[4]=(__bf16)vv.x; wv[5]=(__bf16)vv.y; wv[6]=(__bf16)vv.z; wv[7]=(__bf16)vv.w;
            *reinterpret_cast<bf16x8*>(&sB[lds_off]) = wv;
        }
    }
    __syncthreads();

    const int w  = t >> 6, lane = t & 63;
    const int wr = (w >> 1) * 64;
    const int wc = (w & 1) * 64;
    const int lq = lane >> 4, lr = lane & 15;

    f32x4 acc[4][4] = {};
    #pragma unroll
    for (int ks = 0; ks < 4; ++ks) {
        const int kc = ks * 4 + lq;
        bf16x8 af[4], bfr[4];
        #pragma unroll
        for (int mi = 0; mi < 4; ++mi) {
            int r = wr + mi * 16 + lr;
            af[mi] = *reinterpret_cast<const bf16x8*>(&sA[r * 256 + ((kc * 16) ^ ((r & 7) << 4))]);
        }
        #pragma unroll
        for (int ni = 0; ni < 4; ++ni) {
            int r = wc + ni * 16 + lr;
            bfr[ni] = *reinterpret_cast<const bf16x8*>(&sB[r * 256 + ((kc * 16) ^ ((r & 7) << 4))]);
        }
        #pragma unroll
        for (int mi = 0; mi < 4; ++mi)
            #pragma unroll
            for (int ni = 0; ni < 4; ++ni)
                acc[mi][ni] = __builtin_amdgcn_mfma_f32_16x16x32_bf16(af[mi], bfr[ni], acc[mi][ni], 0, 0, 0);
    }

    float b2v[4];
    #pragma unroll
    for (int ni = 0; ni < 4; ++ni) b2v[ni] = b2[tile_n + wc + ni * 16 + lr];
    float a2v[4][4];
    #pragma unroll
    for (int mi = 0; mi < 4; ++mi)
        #pragma unroll
        for (int j = 0; j < 4; ++j) a2v[mi][j] = a2[tile_m + wr + mi * 16 + lq * 4 + j];

    float rmin[4][4];
    #pragma unroll
    for (int mi = 0; mi < 4; ++mi) {
        #pragma unroll
        for (int j = 0; j < 4; ++j) {
            float m0 = fminf(fmaf(-2.f, acc[mi][0][j], b2v[0]), fmaf(-2.f, acc[mi][1][j], b2v[1]));
            float m1 = fminf(fmaf(-2.f, acc[mi][2][j], b2v[2]), fmaf(-2.f, acc[mi][3][j], b2v[3]));
            float m  = fminf(m0, m1);
            #pragma unroll
            for (int off = 1; off < 16; off <<= 1) m = fminf(m, __shfl_xor(m, off));
            rmin[mi][j] = m + a2v[mi][j];
        }
    }

    float cmin[4];
    #pragma unroll
    for (int ni = 0; ni < 4; ++ni) {
        float m = fmaf(-2.f, acc[0][ni][0], a2v[0][0]);
        #pragma unroll
        for (int mi = 0; mi < 4; ++mi)
            #pragma unroll
            for (int j = 0; j < 4; ++j)
                if (mi | j) m = fminf(m, fmaf(-2.f, acc[mi][ni][j], a2v[mi][j]));
        m = fminf(m, __shfl_xor(m, 16));
        m = fminf(m, __shfl_xor(m, 32));
        cmin[ni] = m + b2v[ni];
    }

    __syncthreads();
    unsigned* rmin_s = reinterpret_cast<unsigned*>(sA);
    unsigned* cmin_s = rmin_s + 128;
    reinterpret_cast<unsigned*>(sA)[t] = 0xFFFFFFFFu;
    __syncthreads();

    if (lr == 0) {
        #pragma unroll
        for (int mi = 0; mi < 4; ++mi)
            #pragma unroll
            for (int j = 0; j < 4; ++j)
                atomicMin(&rmin_s[wr + mi * 16 + lq * 4 + j], fmap(rmin[mi][j]));
    }
    if (lq == 0) {
        #pragma unroll
        for (int ni = 0; ni < 4; ++ni)
            atomicMin(&cmin_s[wc + ni * 16 + lr], fmap(cmin[ni]));
    }
    __syncthreads();

    if (t < 128) atomicMin(&rowmin[tile_m + t], rmin_s[t]);
    else         atomicMin(&colmin[tile_n + t - 128], cmin_s[t - 128]);
}

__global__ void chamfer_finalize_fb(const unsigned* __restrict__ rowmin,
                                    const unsigned* __restrict__ colmin,
                                    float* __restrict__ out) {
    __shared__ double sred[16];
    int t = threadIdx.x;
    double s = 0.0;
    for (int i = t; i < N_PTS; i += 1024)
        s += (double)funmap(rowmin[i]) + (double)funmap(colmin[i]);
    #pragma unroll
    for (int off = 32; off; off >>= 1) s += __shfl_down(s, off);
    if ((t & 63) == 0) sred[t >> 6] = s;
    __syncthreads();
    if (t == 0) {
        double tot = 0.0;
        #pragma unroll
        for (int i = 0; i < 16; ++i) tot += sred[i];
        out[0] = (float)(tot * (1.0 / (double)N_PTS));
    }
}

// ---------------------------------------------------------------------------
extern "C" void kernel_launch(void* const* d_in, const int* in_sizes, int n_in,
                              void* d_out, int out_size, void* d_ws, size_t ws_size,
                              hipStream_t stream) {
    const float* A = (const float*)d_in[0];
    const float* B = (const float*)d_in[1];
    float* out = (float*)d_out;
    char* ws = (char*)d_ws;

    const size_t BF = (size_t)N_PTS * DIM * sizeof(unsigned short);  // 4 MB per cloud
    const size_t need = 2 * BF + 4 * (size_t)(1 << 16);

    if (ws_size >= need) {
        unsigned short* Abf = (unsigned short*)(ws);
        unsigned short* Bbf = (unsigned short*)(ws + BF);
        float*    a2     = (float*)(ws + 2 * BF);
        float*    b2     = (float*)(ws + 2 * BF + (1 << 16));
        unsigned* rowmin = (unsigned*)(ws + 2 * BF + (2 << 16));
        unsigned* colmin = (unsigned*)(ws + 2 * BF + (3 << 16));

        chamfer_prep2<<<(2 * N_PTS) / 4, 256, 0, stream>>>(A, B, Abf, Bbf, a2, b2, rowmin, colmin);
        chamfer_gemm_min3<<<256, 512, 0, stream>>>(Abf, Bbf, a2, b2, rowmin, colmin);
        chamfer_finalize2<<<1, 1024, 0, stream>>>(rowmin, colmin, a2, b2, out);
    } else {
        float*    a2     = (float*)(ws);
        float*    b2     = (float*)(ws + (1 << 16));
        unsigned* rowmin = (unsigned*)(ws + (2 << 16));
        unsigned* colmin = (unsigned*)(ws + (3 << 16));

        chamfer_prep_fb<<<(2 * N_PTS) / 4, 256, 0, stream>>>(A, B, a2, b2, rowmin, colmin);
        dim3 grid(N_PTS / 128, N_PTS / 128);
        chamfer_gemm_min_fb<<<grid, 256, 0, stream>>>(A, B, a2, b2, rowmin, colmin);
        chamfer_finalize_fb<<<1, 1024, 0, stream>>>(rowmin, colmin, out);
    }
}

// Round 4
// 106.070 us; speedup vs baseline: 1.9335x; 1.1279x over previous
//
#include <hip/hip_runtime.h>
#include <hip/hip_bf16.h>

#define N_PTS 16384
#define DIM   128
#define KAUG  160            // 128 data + {1,1,a2hi,a2lo}/{b2hi,b2lo,1,1} + 28 zeros
#define ROWB  (KAUG * 2)     // 320 bytes per augmented row

typedef __bf16 bf16x8 __attribute__((ext_vector_type(8)));
typedef float  f32x4  __attribute__((ext_vector_type(4)));

// Monotone map float -> uint so unsigned atomicMin == float min (handles negatives).
__device__ __forceinline__ unsigned fmap(float f) {
    unsigned u = __float_as_uint(f);
    return (u & 0x80000000u) ? ~u : (u | 0x80000000u);
}
__device__ __forceinline__ float funmap(unsigned u) {
    return __uint_as_float((u & 0x80000000u) ? (u & 0x7FFFFFFFu) : ~u);
}

// Async global->LDS, 16B per lane. LDS dest linear (base + lane*16); swizzled
// layout achieved by pre-swizzling the per-lane GLOBAL source address.
__device__ __forceinline__ void gload_lds16(const void* g, void* l) {
    __builtin_amdgcn_global_load_lds(
        (const __attribute__((address_space(1))) void*)g,
        (__attribute__((address_space(3))) void*)l, 16, 0, 0);
}

// ---------------------------------------------------------------------------
// Prep (v4): builds augmented bf16 matrices.
//   Ax[r] = [ bf16(-2*a[r][k]) (128) | 1, 1, a2hi, a2lo | zeros(28) ]
//   Bx[c] = [ bf16(   b[c][k]) (128) | b2hi, b2lo, 1, 1 | zeros(28) ]
// dot(Ax[r],Bx[c]) = -2 a.b + b2 + a2 = dist^2 (norms at hi/lo bf16 precision).
// Also inits the 4*N min buffer. One wave per row.
// ---------------------------------------------------------------------------
__global__ void chamfer_prep4(const float* __restrict__ A, const float* __restrict__ B,
                              unsigned short* __restrict__ Ax, unsigned short* __restrict__ Bx,
                              unsigned* __restrict__ minbuf) {
    int gtid = blockIdx.x * 256 + threadIdx.x;
    if (gtid < 4 * N_PTS) minbuf[gtid] = 0xFFFFFFFFu;

    int wave = blockIdx.x * 4 + (threadIdx.x >> 6);
    int lane = threadIdx.x & 63;
    int isB  = wave >= N_PTS;
    int row  = isB ? (wave - N_PTS) : wave;
    const float* src = isB ? B : A;
    unsigned short* dst = isB ? Bx : Ax;

    float2 v = *reinterpret_cast<const float2*>(&src[(size_t)row * DIM + lane * 2]);

    float sc = isB ? 1.f : -2.f;
    __bf16 bx = (__bf16)(sc * v.x), by = (__bf16)(sc * v.y);
    ushort2 st;
    st.x = __builtin_bit_cast(unsigned short, bx);
    st.y = __builtin_bit_cast(unsigned short, by);
    *reinterpret_cast<ushort2*>(&dst[(size_t)row * KAUG + lane * 2]) = st;

    float s = fmaf(v.x, v.x, v.y * v.y);
    #pragma unroll
    for (int off = 1; off < 64; off <<= 1) s += __shfl_xor(s, off);

    __bf16 hb = (__bf16)s;
    float  hf = (float)hb;
    __bf16 lb = (__bf16)(s - hf);
    unsigned short hu = __builtin_bit_cast(unsigned short, hb);
    unsigned short lu = __builtin_bit_cast(unsigned short, lb);
    const unsigned short one = 0x3F80;

    if (lane < 16) {
        ushort2 tw; tw.x = 0; tw.y = 0;
        if (lane == 0) { tw.x = isB ? hu : one; tw.y = isB ? lu : one; }
        if (lane == 1) { tw.x = isB ? one : hu; tw.y = isB ? one : lu; }
        *reinterpret_cast<ushort2*>(&dst[(size_t)row * KAUG + 128 + lane * 2]) = tw;
    }
}

// ---------------------------------------------------------------------------
// GEMM+min v4. 512 blocks x 256 threads (4 waves, 2x2), 2 blocks/CU.
// Block b: rows [ (b>>2)*128, +128 ), cols quarter (b&3): 32 tiles of 128.
// A fragments held in registers (loaded once). B tile (128 x 160 bf16 = 40KB)
// double-buffered in LDS, staged via global_load_lds with pre-swizzled source.
// acc = full dist^2 (norms folded into MFMA) -> epilogue is pure min-reduce.
// Row mins accumulate in a register across tiles (1 atomic at end);
// col mins go to per-row-group spread slices (no same-address contention).
// ---------------------------------------------------------------------------
__global__ __launch_bounds__(256, 2)
void chamfer_gemm_min4(const unsigned short* __restrict__ Ax,
                       const unsigned short* __restrict__ Bx,
                       unsigned* __restrict__ rowminS,    // [2][N_PTS]
                       unsigned* __restrict__ colminS) {  // [2][N_PTS]
    __shared__ __align__(16) unsigned char sB[2][40960];

    const int b   = blockIdx.x;
    const int tm  = (b >> 2) * 128;
    const int tn0 = (b & 3) * 32;

    const int t = threadIdx.x, w = t >> 6, lane = t & 63;
    const int lq = lane >> 4, lr = lane & 15;
    const int wr = (w >> 1) * 64, wc = (w & 1) * 64;

    // ---- A fragments -> registers (20 x 16B per lane, one time) ----
    bf16x8 af[4][5];
    #pragma unroll
    for (int mi = 0; mi < 4; ++mi)
        #pragma unroll
        for (int ks = 0; ks < 5; ++ks) {
            int row = tm + wr + mi * 16 + lr;
            int kc  = ks * 4 + lq;
            af[mi][ks] = *reinterpret_cast<const bf16x8*>(&Ax[(size_t)row * KAUG + kc * 8]);
        }

    // ---- stage tile 0 ----
    #pragma unroll
    for (int j = 0; j < 10; ++j) {
        int chunk = j * 256 + t;                // 0..2559 (wave-linear dest)
        int r = chunk / 20;
        int s = chunk - r * 20;
        int c = (s < 16) ? (s ^ (r & 7)) : (16 + ((s - 16) ^ (r & 3)));
        gload_lds16(Bx + (size_t)(tn0 * 128 + r) * KAUG + c * 8, sB[0] + chunk * 16);
    }
    __syncthreads();

    const int own_row = tm + wr + ((lr >> 2) << 4) + (lq << 2) + (lr & 3);
    const int ni_own  = ((lq & 1) << 1) | (lq >> 1);
    float rmin_run = 3.4e38f;

    for (int it = 0; it < 32; ++it) {
        const int cur = it & 1;
        const int tn  = tn0 + it;

        if (it + 1 < 32) {
            #pragma unroll
            for (int j = 0; j < 10; ++j) {
                int chunk = j * 256 + t;
                int r = chunk / 20;
                int s = chunk - r * 20;
                int c = (s < 16) ? (s ^ (r & 7)) : (16 + ((s - 16) ^ (r & 3)));
                gload_lds16(Bx + (size_t)((tn + 1) * 128 + r) * KAUG + c * 8,
                            sB[cur ^ 1] + chunk * 16);
            }
        }

        // ---- MFMA: 64x64 per wave, K=160 in 5 k-steps; acc = dist^2 ----
        f32x4 acc[4][4] = {};
        #pragma unroll
        for (int ks = 0; ks < 5; ++ks) {
            bf16x8 bfr[4];
            #pragma unroll
            for (int ni = 0; ni < 4; ++ni) {
                int r = wc + ni * 16 + lr;
                int slot = (ks < 4) ? ((ks * 4 + lq) ^ (r & 7)) : (16 + (lq ^ (r & 3)));
                bfr[ni] = *reinterpret_cast<const bf16x8*>(&sB[cur][r * ROWB + slot * 16]);
            }
            #pragma unroll
            for (int mi = 0; mi < 4; ++mi)
                #pragma unroll
                for (int ni = 0; ni < 4; ++ni)
                    acc[mi][ni] = __builtin_amdgcn_mfma_f32_16x16x32_bf16(af[mi][ks], bfr[ni], acc[mi][ni], 0, 0, 0);
        }

        // ---- row mins: v[mi*4+j] = min over 4 ni ----
        float v[16];
        #pragma unroll
        for (int mi = 0; mi < 4; ++mi)
            #pragma unroll
            for (int j = 0; j < 4; ++j)
                v[mi * 4 + j] = fminf(fminf(acc[mi][0][j], acc[mi][1][j]),
                                      fminf(acc[mi][2][j], acc[mi][3][j]));
        // reduce-scatter 16 vars over 16 lr lanes
        #pragma unroll
        for (int k = 0; k < 8; ++k) {
            float s = (lr & 8) ? v[k] : v[k + 8];
            float r = __shfl_xor(s, 8);
            v[k] = (lr & 8) ? fminf(v[k + 8], r) : fminf(v[k], r);
        }
        #pragma unroll
        for (int k = 0; k < 4; ++k) {
            float s = (lr & 4) ? v[k] : v[k + 4];
            float r = __shfl_xor(s, 4);
            v[k] = (lr & 4) ? fminf(v[k + 4], r) : fminf(v[k], r);
        }
        #pragma unroll
        for (int k = 0; k < 2; ++k) {
            float s = (lr & 2) ? v[k] : v[k + 2];
            float r = __shfl_xor(s, 2);
            v[k] = (lr & 2) ? fminf(v[k + 2], r) : fminf(v[k], r);
        }
        {
            float s = (lr & 1) ? v[0] : v[1];
            float r = __shfl_xor(s, 1);
            v[0] = (lr & 1) ? fminf(v[1], r) : fminf(v[0], r);
        }
        rmin_run = fminf(rmin_run, v[0]);

        // ---- col mins: cp[ni] = min over 16 (mi,j) ----
        float cp[4];
        #pragma unroll
        for (int ni = 0; ni < 4; ++ni) {
            float m0 = fminf(fminf(acc[0][ni][0], acc[0][ni][1]), fminf(acc[0][ni][2], acc[0][ni][3]));
            float m1 = fminf(fminf(acc[1][ni][0], acc[1][ni][1]), fminf(acc[1][ni][2], acc[1][ni][3]));
            float m2 = fminf(fminf(acc[2][ni][0], acc[2][ni][1]), fminf(acc[2][ni][2], acc[2][ni][3]));
            float m3 = fminf(fminf(acc[3][ni][0], acc[3][ni][1]), fminf(acc[3][ni][2], acc[3][ni][3]));
            cp[ni] = fminf(fminf(m0, m1), fminf(m2, m3));
        }
        #pragma unroll
        for (int k = 0; k < 2; ++k) {
            float s = (lane & 16) ? cp[k] : cp[k + 2];
            float r = __shfl_xor(s, 16);
            cp[k] = (lane & 16) ? fminf(cp[k + 2], r) : fminf(cp[k], r);
        }
        float cfin;
        {
            float s = (lane & 32) ? cp[0] : cp[1];
            float r = __shfl_xor(s, 32);
            cfin = (lane & 32) ? fminf(cp[1], r) : fminf(cp[0], r);
        }
        const int own_col = tn * 128 + wc + ni_own * 16 + lr;

        __syncthreads();   // all waves done with sB[cur]; this iter's prefetch landed

        atomicMin(&colminS[(size_t)(w >> 1) * N_PTS + own_col], fmap(cfin));
    }

    atomicMin(&rowminS[(size_t)(w & 1) * N_PTS + own_row], fmap(rmin_run));
}

// ---------------------------------------------------------------------------
// Finalize v4: mean over rows of min(2 slices) + mean over cols of min(2 slices).
// ---------------------------------------------------------------------------
__global__ void chamfer_finalize4(const unsigned* __restrict__ rowminS,
                                  const unsigned* __restrict__ colminS,
                                  float* __restrict__ out) {
    __shared__ double sred[16];
    int t = threadIdx.x;
    double s = 0.0;
    for (int i = t; i < N_PTS; i += 1024) {
        unsigned rm = min(rowminS[i], rowminS[i + N_PTS]);
        unsigned cm = min(colminS[i], colminS[i + N_PTS]);
        s += (double)funmap(rm) + (double)funmap(cm);
    }
    #pragma unroll
    for (int off = 32; off; off >>= 1) s += __shfl_down(s, off);
    if ((t & 63) == 0) sred[t >> 6] = s;
    __syncthreads();
    if (t == 0) {
        double tot = 0.0;
        #pragma unroll
        for (int i = 0; i < 16; ++i) tot += sred[i];
        out[0] = (float)(tot * (1.0 / (double)N_PTS));
    }
}

// ---------------------------------------------------------------------------
// Fallback path = round-3 kernels (known-passing, 119 us) if ws too small.
// ---------------------------------------------------------------------------
__global__ void chamfer_prep2(const float* __restrict__ A, const float* __restrict__ B,
                              unsigned short* __restrict__ Abf, unsigned short* __restrict__ Bbf,
                              float* __restrict__ a2, float* __restrict__ b2,
                              unsigned* __restrict__ rowmin, unsigned* __restrict__ colmin) {
    int wave = blockIdx.x * 4 + (threadIdx.x >> 6);
    int lane = threadIdx.x & 63;
    int isB  = wave >= N_PTS;
    int row  = isB ? (wave - N_PTS) : wave;
    const float* src = isB ? B : A;
    unsigned short* dst = isB ? Bbf : Abf;

    float2 v = *reinterpret_cast<const float2*>(&src[(size_t)row * DIM + lane * 2]);
    __bf16 bx = (__bf16)v.x, by = (__bf16)v.y;
    ushort2 st;
    st.x = __builtin_bit_cast(unsigned short, bx);
    st.y = __builtin_bit_cast(unsigned short, by);
    *reinterpret_cast<ushort2*>(&dst[(size_t)row * DIM + lane * 2]) = st;

    float s = fmaf(v.x, v.x, v.y * v.y);
    #pragma unroll
    for (int off = 32; off; off >>= 1) s += __shfl_down(s, off);
    if (lane == 0) {
        if (isB) { b2[row] = s; colmin[row] = 0xFFFFFFFFu; }
        else     { a2[row] = s; rowmin[row] = 0xFFFFFFFFu; }
    }
}

__global__ __launch_bounds__(512, 2)
void chamfer_gemm_min3(const unsigned short* __restrict__ Abf, const unsigned short* __restrict__ Bbf,
                       const float* __restrict__ a2, const float* __restrict__ b2,
                       unsigned* __restrict__ rowmin, unsigned* __restrict__ colmin) {
    __shared__ __align__(16) unsigned char sA[65536];
    __shared__ __align__(16) unsigned char sB2[2][32768];

    const int b = blockIdx.x;
    const int tm_base = (b >> 2) * 256;
    const int tn0 = (b & 3) * 32;

    const int t = threadIdx.x;
    const int w = t >> 6, lane = t & 63;
    const int lq = lane >> 4, lr = lane & 15;
    const int wr = (w >> 1) * 64;
    const int wc = (w & 1) * 64;

    #pragma unroll
    for (int j = 0; j < 8; ++j) {
        int chunk = ((w << 3) + j) * 64 + lane;
        int r = chunk >> 4, kc = (chunk & 15) ^ (r & 7);
        gload_lds16(Abf + (size_t)(tm_base + r) * DIM + kc * 8, sA + chunk * 16);
    }
    #pragma unroll
    for (int j = 0; j < 4; ++j) {
        int chunk = ((w << 2) + j) * 64 + lane;
        int r = chunk >> 4, kc = (chunk & 15) ^ (r & 7);
        gload_lds16(Bbf + (size_t)(tn0 * 128 + r) * DIM + kc * 8, sB2[0] + chunk * 16);
    }

    float a2v[4][4];
    #pragma unroll
    for (int mi = 0; mi < 4; ++mi) {
        float4 q = *reinterpret_cast<const float4*>(&a2[tm_base + wr + mi * 16 + lq * 4]);
        a2v[mi][0] = q.x; a2v[mi][1] = q.y; a2v[mi][2] = q.z; a2v[mi][3] = q.w;
    }
    __syncthreads();

    for (int it = 0; it < 32; ++it) {
        const int cur = it & 1;
        const int tn = tn0 + it;

        if (it + 1 < 32) {
            #pragma unroll
            for (int j = 0; j < 4; ++j) {
                int chunk = ((w << 2) + j) * 64 + lane;
                int r = chunk >> 4, kc = (chunk & 15) ^ (r & 7);
                gload_lds16(Bbf + (size_t)((tn + 1) * 128 + r) * DIM + kc * 8,
                            sB2[cur ^ 1] + chunk * 16);
            }
        }

        f32x4 acc[4][4] = {};
        #pragma unroll
        for (int ks = 0; ks < 4; ++ks) {
            const int kc = ks * 4 + lq;
            bf16x8 af2[4], bfr[4];
            #pragma unroll
            for (int mi = 0; mi < 4; ++mi) {
                int r = wr + mi * 16 + lr;
                af2[mi] = *reinterpret_cast<const bf16x8*>(&sA[r * 256 + ((kc * 16) ^ ((r & 7) << 4))]);
            }
            #pragma unroll
            for (int ni = 0; ni < 4; ++ni) {
                int r = wc + ni * 16 + lr;
                bfr[ni] = *reinterpret_cast<const bf16x8*>(&sB2[cur][r * 256 + ((kc * 16) ^ ((r & 7) << 4))]);
            }
            #pragma unroll
            for (int mi = 0; mi < 4; ++mi)
                #pragma unroll
                for (int ni = 0; ni < 4; ++ni)
                    acc[mi][ni] = __builtin_amdgcn_mfma_f32_16x16x32_bf16(af2[mi], bfr[ni], acc[mi][ni], 0, 0, 0);
        }

        const int col_base = tn * 128 + wc;
        float b2v[4];
        #pragma unroll
        for (int ni = 0; ni < 4; ++ni) b2v[ni] = b2[col_base + ni * 16 + lr];

        float v[16];
        #pragma unroll
        for (int mi = 0; mi < 4; ++mi) {
            #pragma unroll
            for (int j = 0; j < 4; ++j) {
                float m = fmaf(-2.f, acc[mi][0][j], b2v[0]);
                m = fminf(m, fmaf(-2.f, acc[mi][1][j], b2v[1]));
                m = fminf(m, fmaf(-2.f, acc[mi][2][j], b2v[2]));
                m = fminf(m, fmaf(-2.f, acc[mi][3][j], b2v[3]));
                v[mi * 4 + j] = m;
            }
        }
        #pragma unroll
        for (int k = 0; k < 8; ++k) {
            float s = (lr & 8) ? v[k] : v[k + 8];
            float r = __shfl_xor(s, 8);
            v[k] = (lr & 8) ? fminf(v[k + 8], r) : fminf(v[k], r);
        }
        #pragma unroll
        for (int k = 0; k < 4; ++k) {
            float s = (lr & 4) ? v[k] : v[k + 4];
            float r = __shfl_xor(s, 4);
            v[k] = (lr & 4) ? fminf(v[k + 4], r) : fminf(v[k], r);
        }
        #pragma unroll
        for (int k = 0; k < 2; ++k) {
            float s = (lr & 2) ? v[k] : v[k + 2];
            float r = __shfl_xor(s, 2);
            v[k] = (lr & 2) ? fminf(v[k + 2], r) : fminf(v[k], r);
        }
        {
            float s = (lr & 1) ? v[0] : v[1];
            float r = __shfl_xor(s, 1);
            v[0] = (lr & 1) ? fminf(v[1], r) : fminf(v[0], r);
        }
        const int own_row = tm_base + wr + ((lr >> 2) << 4) + (lq << 2) + (lr & 3);

        float cp[4];
        #pragma unroll
        for (int ni = 0; ni < 4; ++ni) {
            float m = fmaf(-2.f, acc[0][ni][0], a2v[0][0]);
            #pragma unroll
            for (int mi = 0; mi < 4; ++mi)
                #pragma unroll
                for (int j = 0; j < 4; ++j)
                    if (mi | j) m = fminf(m, fmaf(-2.f, acc[mi][ni][j], a2v[mi][j]));
            cp[ni] = m;
        }
        #pragma unroll
        for (int k = 0; k < 2; ++k) {
            float s = (lane & 16) ? cp[k] : cp[k + 2];
            float r = __shfl_xor(s, 16);
            cp[k] = (lane & 16) ? fminf(cp[k + 2], r) : fminf(cp[k], r);
        }
        float cfin;
        {
            float s = (lane & 32) ? cp[0] : cp[1];
            float r = __shfl_xor(s, 32);
            cfin = (lane & 32) ? fminf(cp[1], r) : fminf(cp[0], r);
        }
        const int ni_own = ((lq & 1) << 1) | (lq >> 1);
        const int own_col = col_base + ni_own * 16 + lr;

        __syncthreads();

        atomicMin(&rowmin[own_row], fmap(v[0]));
        atomicMin(&colmin[own_col], fmap(cfin));
    }
}

__global__ void chamfer_finalize2(const unsigned* __restrict__ rowmin,
                                  const unsigned* __restrict__ colmin,
                                  const float* __restrict__ a2, const float* __restrict__ b2,
                                  float* __restrict__ out) {
    __shared__ double sred[16];
    int t = threadIdx.x;
    double s = 0.0;
    for (int i = t; i < N_PTS; i += 1024)
        s += ((double)funmap(rowmin[i]) + (double)a2[i])
           + ((double)funmap(colmin[i]) + (double)b2[i]);
    #pragma unroll
    for (int off = 32; off; off >>= 1) s += __shfl_down(s, off);
    if ((t & 63) == 0) sred[t >> 6] = s;
    __syncthreads();
    if (t == 0) {
        double tot = 0.0;
        #pragma unroll
        for (int i = 0; i < 16; ++i) tot += sred[i];
        out[0] = (float)(tot * (1.0 / (double)N_PTS));
    }
}

// ---------------------------------------------------------------------------
extern "C" void kernel_launch(void* const* d_in, const int* in_sizes, int n_in,
                              void* d_out, int out_size, void* d_ws, size_t ws_size,
                              hipStream_t stream) {
    const float* A = (const float*)d_in[0];
    const float* B = (const float*)d_in[1];
    float* out = (float*)d_out;
    char* ws = (char*)d_ws;

    const size_t SZ4   = (size_t)N_PTS * KAUG * sizeof(unsigned short);  // 5.24 MB
    const size_t need4 = 2 * SZ4 + 4 * (size_t)N_PTS * 4;                // ~10.75 MB

    const size_t BF    = (size_t)N_PTS * DIM * sizeof(unsigned short);   // 4 MB
    const size_t need3 = 2 * BF + 4 * (size_t)(1 << 16);                 // ~8.65 MB

    if (ws_size >= need4) {
        unsigned short* Ax = (unsigned short*)(ws);
        unsigned short* Bx = (unsigned short*)(ws + SZ4);
        unsigned* minbuf   = (unsigned*)(ws + 2 * SZ4);
        unsigned* rowminS  = minbuf;                     // [2][N]
        unsigned* colminS  = minbuf + 2 * N_PTS;         // [2][N]

        chamfer_prep4<<<(2 * N_PTS) / 4, 256, 0, stream>>>(A, B, Ax, Bx, minbuf);
        chamfer_gemm_min4<<<512, 256, 0, stream>>>(Ax, Bx, rowminS, colminS);
        chamfer_finalize4<<<1, 1024, 0, stream>>>(rowminS, colminS, out);
    } else if (ws_size >= need3) {
        unsigned short* Abf = (unsigned short*)(ws);
        unsigned short* Bbf = (unsigned short*)(ws + BF);
        float*    a2     = (float*)(ws + 2 * BF);
        float*    b2     = (float*)(ws + 2 * BF + (1 << 16));
        unsigned* rowmin = (unsigned*)(ws + 2 * BF + (2 << 16));
        unsigned* colmin = (unsigned*)(ws + 2 * BF + (3 << 16));

        chamfer_prep2<<<(2 * N_PTS) / 4, 256, 0, stream>>>(A, B, Abf, Bbf, a2, b2, rowmin, colmin);
        chamfer_gemm_min3<<<256, 512, 0, stream>>>(Abf, Bbf, a2, b2, rowmin, colmin);
        chamfer_finalize2<<<1, 1024, 0, stream>>>(rowmin, colmin, a2, b2, out);
    }
}

// Round 5
// 102.080 us; speedup vs baseline: 2.0091x; 1.0391x over previous
//
#include <hip/hip_runtime.h>
#include <hip/hip_bf16.h>

#define N_PTS 16384
#define DIM   128
#define KAUG  144            // 128 data + {1,1,a2hi,a2lo}/{b2hi,b2lo,1,1} + 12 zeros
#define ROWB  (KAUG * 2)     // 288 bytes per augmented row
#define NCHUNK 18            // 16B chunks per row

typedef __bf16 bf16x8 __attribute__((ext_vector_type(8)));
typedef float  f32x4  __attribute__((ext_vector_type(4)));
typedef float  f32x16 __attribute__((ext_vector_type(16)));

// Monotone map float -> uint so unsigned atomicMin == float min (handles negatives).
__device__ __forceinline__ unsigned fmap(float f) {
    unsigned u = __float_as_uint(f);
    return (u & 0x80000000u) ? ~u : (u | 0x80000000u);
}
__device__ __forceinline__ float funmap(unsigned u) {
    return __uint_as_float((u & 0x80000000u) ? (u & 0x7FFFFFFFu) : ~u);
}

__device__ __forceinline__ void gload_lds16(const void* g, void* l) {
    __builtin_amdgcn_global_load_lds(
        (const __attribute__((address_space(1))) void*)g,
        (__attribute__((address_space(3))) void*)l, 16, 0, 0);
}

// ---------------------------------------------------------------------------
// Prep v5: augmented bf16 rows, KAUG=144.
//   Ax[r] = [ bf16(-2*a[r][k]) (128) | 1, 1, a2hi, a2lo | zeros(12) ]
//   Bx[c] = [ bf16(   b[c][k]) (128) | b2hi, b2lo, 1, 1 | zeros(12) ]
// dot(Ax[r],Bx[c]) = -2 a.b + b2 + a2 = dist^2. Also inits 4*N min buffer.
// ---------------------------------------------------------------------------
__global__ void chamfer_prep5(const float* __restrict__ A, const float* __restrict__ B,
                              unsigned short* __restrict__ Ax, unsigned short* __restrict__ Bx,
                              unsigned* __restrict__ minbuf) {
    int gtid = blockIdx.x * 256 + threadIdx.x;
    if (gtid < 4 * N_PTS) minbuf[gtid] = 0xFFFFFFFFu;

    int wave = blockIdx.x * 4 + (threadIdx.x >> 6);
    int lane = threadIdx.x & 63;
    int isB  = wave >= N_PTS;
    int row  = isB ? (wave - N_PTS) : wave;
    const float* src = isB ? B : A;
    unsigned short* dst = isB ? Bx : Ax;

    float2 v = *reinterpret_cast<const float2*>(&src[(size_t)row * DIM + lane * 2]);

    float sc = isB ? 1.f : -2.f;
    __bf16 bx = (__bf16)(sc * v.x), by = (__bf16)(sc * v.y);
    ushort2 st;
    st.x = __builtin_bit_cast(unsigned short, bx);
    st.y = __builtin_bit_cast(unsigned short, by);
    *reinterpret_cast<ushort2*>(&dst[(size_t)row * KAUG + lane * 2]) = st;

    float s = fmaf(v.x, v.x, v.y * v.y);
    #pragma unroll
    for (int off = 1; off < 64; off <<= 1) s += __shfl_xor(s, off);

    __bf16 hb = (__bf16)s;
    float  hf = (float)hb;
    __bf16 lb = (__bf16)(s - hf);
    unsigned short hu = __builtin_bit_cast(unsigned short, hb);
    unsigned short lu = __builtin_bit_cast(unsigned short, lb);
    const unsigned short one = 0x3F80;

    if (lane < 8) {  // k = 128..143
        ushort2 tw; tw.x = 0; tw.y = 0;
        if (lane == 0) { tw.x = isB ? hu : one; tw.y = isB ? lu : one; }
        if (lane == 1) { tw.x = isB ? one : hu; tw.y = isB ? one : lu; }
        *reinterpret_cast<ushort2*>(&dst[(size_t)row * KAUG + 128 + lane * 2]) = tw;
    }
}

// ---------------------------------------------------------------------------
// GEMM+min v5: 512 blocks x 256 threads (4 waves, 2x2), 32x32x16 MFMA.
// Block b: rows [(b>>2)*128, +128), col quarter (b&3): 32 tiles of 128 cols.
// A fragments in registers (one-time load); B tile (128 x 144 bf16 = 36KB)
// double-buffered in LDS via global_load_lds with pre-swizzled source.
// acc = full dist^2. Row minima accumulate in registers across all tiles
// (one reduce-scatter + atomic at end); col minima 1 atomic/lane/tile.
// C/D layout (32x32x16): col = lane&31, row = (reg&3) + 8*(reg>>2) + 4*hi.
// ---------------------------------------------------------------------------
__global__ __launch_bounds__(256, 2)
void chamfer_gemm_min5(const unsigned short* __restrict__ Ax,
                       const unsigned short* __restrict__ Bx,
                       unsigned* __restrict__ rowminS,    // [2][N_PTS]
                       unsigned* __restrict__ colminS) {  // [2][N_PTS]
    __shared__ __align__(16) unsigned char sB[2][36864];

    const int b   = blockIdx.x;
    const int tm  = (b >> 2) * 128;
    const int tn0 = (b & 3) * 32;

    const int t = threadIdx.x, w = t >> 6, lane = t & 63;
    const int ll = lane & 31, hi = lane >> 5;
    const int wr = (w >> 1) * 64, wc = (w & 1) * 64;

    // ---- A fragments -> registers: af[mi][ks], row = tm+wr+mi*32+ll ----
    bf16x8 af[2][9];
    #pragma unroll
    for (int mi = 0; mi < 2; ++mi) {
        const unsigned short* ap = Ax + (size_t)(tm + wr + mi * 32 + ll) * KAUG + hi * 8;
        #pragma unroll
        for (int ks = 0; ks < 9; ++ks)
            af[mi][ks] = *reinterpret_cast<const bf16x8*>(ap + ks * 16);
    }

    // ---- staging offsets (loop-invariant): 2304 chunks, 9 per thread ----
    int goff[9];   // element offset within a 128-row B panel (pre-swizzled)
    #pragma unroll
    for (int j = 0; j < 9; ++j) {
        int chunk = j * 256 + t;
        int r = chunk / NCHUNK;
        int s = chunk - r * NCHUNK;
        int c = (s < 16) ? (s ^ (r & 7)) : (16 + ((s - 16) ^ (r & 1)));
        goff[j] = r * KAUG + c * 8;
    }

    // ---- stage tile 0 ----
    {
        const unsigned short* bp = Bx + (size_t)tn0 * 128 * KAUG;
        #pragma unroll
        for (int j = 0; j < 9; ++j)
            gload_lds16(bp + goff[j], sB[0] + (j * 256 + t) * 16);
    }
    __syncthreads();

    float rmin_part[32];
    #pragma unroll
    for (int k = 0; k < 32; ++k) rmin_part[k] = 3.4e38f;

    // B-read lane constants
    const int rA = wc + ll;          // nj=0 row in tile
    const int rB = wc + 32 + ll;     // nj=1 row in tile

    for (int it = 0; it < 32; ++it) {
        const int cur = it & 1;
        const int tn  = tn0 + it;

        if (it + 1 < 32) {
            const unsigned short* bp = Bx + (size_t)(tn + 1) * 128 * KAUG;
            #pragma unroll
            for (int j = 0; j < 9; ++j)
                gload_lds16(bp + goff[j], sB[cur ^ 1] + (j * 256 + t) * 16);
        }

        // ---- MFMA: 64x64 per wave as 2x2 32x32 tiles, 9 k-steps ----
        f32x16 acc[2][2] = {};
        #pragma unroll
        for (int ks = 0; ks < 9; ++ks) {
            const int c = ks * 2 + hi;
            const int sA0 = (c < 16) ? (c ^ (rA & 7)) : (16 + ((c - 16) ^ (rA & 1)));
            const int sB1 = (c < 16) ? (c ^ (rB & 7)) : (16 + ((c - 16) ^ (rB & 1)));
            bf16x8 b0 = *reinterpret_cast<const bf16x8*>(&sB[cur][rA * ROWB + sA0 * 16]);
            bf16x8 b1 = *reinterpret_cast<const bf16x8*>(&sB[cur][rB * ROWB + sB1 * 16]);
            #pragma unroll
            for (int mi = 0; mi < 2; ++mi) {
                acc[mi][0] = __builtin_amdgcn_mfma_f32_32x32x16_bf16(af[mi][ks], b0, acc[mi][0], 0, 0, 0);
                acc[mi][1] = __builtin_amdgcn_mfma_f32_32x32x16_bf16(af[mi][ks], b1, acc[mi][1], 0, 0, 0);
            }
        }

        // ---- row minima: register accumulation (no shuffles) ----
        #pragma unroll
        for (int mi = 0; mi < 2; ++mi)
            #pragma unroll
            for (int reg = 0; reg < 16; ++reg)
                rmin_part[mi * 16 + reg] =
                    fminf(rmin_part[mi * 16 + reg], fminf(acc[mi][0][reg], acc[mi][1][reg]));

        // ---- col minima: per-lane tree + cross-hi combine, 1 atomic/lane ----
        float cm0 = acc[0][0][0], cm1 = acc[0][1][0];
        #pragma unroll
        for (int mi = 0; mi < 2; ++mi)
            #pragma unroll
            for (int reg = 0; reg < 16; ++reg) {
                if (mi | reg) {
                    cm0 = fminf(cm0, acc[mi][0][reg]);
                    cm1 = fminf(cm1, acc[mi][1][reg]);
                }
            }
        cm0 = fminf(cm0, __shfl_xor(cm0, 32));
        cm1 = fminf(cm1, __shfl_xor(cm1, 32));
        float cmSel = hi ? cm1 : cm0;                       // lane fires its own nj=hi
        const int own_col = tn * 128 + wc + hi * 32 + ll;   // 64 distinct cols per wave

        __syncthreads();   // all waves done with sB[cur]; prefetch landed

        atomicMin(&colminS[(size_t)(w >> 1) * N_PTS + own_col], fmap(cmSel));
    }

    // ---- final row reduce-scatter: 32 vars over 32 ll-lanes, 5 stages ----
    #pragma unroll
    for (int s = 16; s >= 1; s >>= 1) {
        #pragma unroll
        for (int k = 0; k < 16; ++k) {
            if (k < s) {
                float snd = (ll & s) ? rmin_part[k] : rmin_part[k + s];
                float r = __shfl_xor(snd, s);
                rmin_part[k] = (ll & s) ? fminf(rmin_part[k + s], r) : fminf(rmin_part[k], r);
            }
        }
    }
    // lane (hi,ll) owns var ll: row = wr + (ll>>4)*32 + (ll&3) + 8*((ll>>2)&3) + 4*hi
    const int own_row = tm + wr + ((ll >> 4) << 5) + (ll & 3) + (((ll >> 2) & 3) << 3) + (hi << 2);
    atomicMin(&rowminS[(size_t)(w & 1) * N_PTS + own_row], fmap(rmin_part[0]));
}

// ---------------------------------------------------------------------------
// Finalize: mean over rows of min(2 slices) + mean over cols of min(2 slices).
// ---------------------------------------------------------------------------
__global__ void chamfer_finalize4(const unsigned* __restrict__ rowminS,
                                  const unsigned* __restrict__ colminS,
                                  float* __restrict__ out) {
    __shared__ double sred[16];
    int t = threadIdx.x;
    double s = 0.0;
    for (int i = t; i < N_PTS; i += 1024) {
        unsigned rm = min(rowminS[i], rowminS[i + N_PTS]);
        unsigned cm = min(colminS[i], colminS[i + N_PTS]);
        s += (double)funmap(rm) + (double)funmap(cm);
    }
    #pragma unroll
    for (int off = 32; off; off >>= 1) s += __shfl_down(s, off);
    if ((t & 63) == 0) sred[t >> 6] = s;
    __syncthreads();
    if (t == 0) {
        double tot = 0.0;
        #pragma unroll
        for (int i = 0; i < 16; ++i) tot += sred[i];
        out[0] = (float)(tot * (1.0 / (double)N_PTS));
    }
}

// ---------------------------------------------------------------------------
// Fallback path = round-3 kernels (known-passing) if ws too small.
// ---------------------------------------------------------------------------
__global__ void chamfer_prep2(const float* __restrict__ A, const float* __restrict__ B,
                              unsigned short* __restrict__ Abf, unsigned short* __restrict__ Bbf,
                              float* __restrict__ a2, float* __restrict__ b2,
                              unsigned* __restrict__ rowmin, unsigned* __restrict__ colmin) {
    int wave = blockIdx.x * 4 + (threadIdx.x >> 6);
    int lane = threadIdx.x & 63;
    int isB  = wave >= N_PTS;
    int row  = isB ? (wave - N_PTS) : wave;
    const float* src = isB ? B : A;
    unsigned short* dst = isB ? Bbf : Abf;

    float2 v = *reinterpret_cast<const float2*>(&src[(size_t)row * DIM + lane * 2]);
    __bf16 bx = (__bf16)v.x, by = (__bf16)v.y;
    ushort2 st;
    st.x = __builtin_bit_cast(unsigned short, bx);
    st.y = __builtin_bit_cast(unsigned short, by);
    *reinterpret_cast<ushort2*>(&dst[(size_t)row * DIM + lane * 2]) = st;

    float s = fmaf(v.x, v.x, v.y * v.y);
    #pragma unroll
    for (int off = 32; off; off >>= 1) s += __shfl_down(s, off);
    if (lane == 0) {
        if (isB) { b2[row] = s; colmin[row] = 0xFFFFFFFFu; }
        else     { a2[row] = s; rowmin[row] = 0xFFFFFFFFu; }
    }
}

__global__ __launch_bounds__(512, 2)
void chamfer_gemm_min3(const unsigned short* __restrict__ Abf, const unsigned short* __restrict__ Bbf,
                       const float* __restrict__ a2, const float* __restrict__ b2,
                       unsigned* __restrict__ rowmin, unsigned* __restrict__ colmin) {
    __shared__ __align__(16) unsigned char sA[65536];
    __shared__ __align__(16) unsigned char sB2[2][32768];

    const int b = blockIdx.x;
    const int tm_base = (b >> 2) * 256;
    const int tn0 = (b & 3) * 32;

    const int t = threadIdx.x;
    const int w = t >> 6, lane = t & 63;
    const int lq = lane >> 4, lr = lane & 15;
    const int wr = (w >> 1) * 64;
    const int wc = (w & 1) * 64;

    #pragma unroll
    for (int j = 0; j < 8; ++j) {
        int chunk = ((w << 3) + j) * 64 + lane;
        int r = chunk >> 4, kc = (chunk & 15) ^ (r & 7);
        gload_lds16(Abf + (size_t)(tm_base + r) * DIM + kc * 8, sA + chunk * 16);
    }
    #pragma unroll
    for (int j = 0; j < 4; ++j) {
        int chunk = ((w << 2) + j) * 64 + lane;
        int r = chunk >> 4, kc = (chunk & 15) ^ (r & 7);
        gload_lds16(Bbf + (size_t)(tn0 * 128 + r) * DIM + kc * 8, sB2[0] + chunk * 16);
    }

    float a2v[4][4];
    #pragma unroll
    for (int mi = 0; mi < 4; ++mi) {
        float4 q = *reinterpret_cast<const float4*>(&a2[tm_base + wr + mi * 16 + lq * 4]);
        a2v[mi][0] = q.x; a2v[mi][1] = q.y; a2v[mi][2] = q.z; a2v[mi][3] = q.w;
    }
    __syncthreads();

    for (int it = 0; it < 32; ++it) {
        const int cur = it & 1;
        const int tn = tn0 + it;

        if (it + 1 < 32) {
            #pragma unroll
            for (int j = 0; j < 4; ++j) {
                int chunk = ((w << 2) + j) * 64 + lane;
                int r = chunk >> 4, kc = (chunk & 15) ^ (r & 7);
                gload_lds16(Bbf + (size_t)((tn + 1) * 128 + r) * DIM + kc * 8,
                            sB2[cur ^ 1] + chunk * 16);
            }
        }

        f32x4 acc[4][4] = {};
        #pragma unroll
        for (int ks = 0; ks < 4; ++ks) {
            const int kc = ks * 4 + lq;
            bf16x8 af2[4], bfr[4];
            #pragma unroll
            for (int mi = 0; mi < 4; ++mi) {
                int r = wr + mi * 16 + lr;
                af2[mi] = *reinterpret_cast<const bf16x8*>(&sA[r * 256 + ((kc * 16) ^ ((r & 7) << 4))]);
            }
            #pragma unroll
            for (int ni = 0; ni < 4; ++ni) {
                int r = wc + ni * 16 + lr;
                bfr[ni] = *reinterpret_cast<const bf16x8*>(&sB2[cur][r * 256 + ((kc * 16) ^ ((r & 7) << 4))]);
            }
            #pragma unroll
            for (int mi = 0; mi < 4; ++mi)
                #pragma unroll
                for (int ni = 0; ni < 4; ++ni)
                    acc[mi][ni] = __builtin_amdgcn_mfma_f32_16x16x32_bf16(af2[mi], bfr[ni], acc[mi][ni], 0, 0, 0);
        }

        const int col_base = tn * 128 + wc;
        float b2v[4];
        #pragma unroll
        for (int ni = 0; ni < 4; ++ni) b2v[ni] = b2[col_base + ni * 16 + lr];

        float v[16];
        #pragma unroll
        for (int mi = 0; mi < 4; ++mi) {
            #pragma unroll
            for (int j = 0; j < 4; ++j) {
                float m = fmaf(-2.f, acc[mi][0][j], b2v[0]);
                m = fminf(m, fmaf(-2.f, acc[mi][1][j], b2v[1]));
                m = fminf(m, fmaf(-2.f, acc[mi][2][j], b2v[2]));
                m = fminf(m, fmaf(-2.f, acc[mi][3][j], b2v[3]));
                v[mi * 4 + j] = m;
            }
        }
        #pragma unroll
        for (int k = 0; k < 8; ++k) {
            float s = (lr & 8) ? v[k] : v[k + 8];
            float r = __shfl_xor(s, 8);
            v[k] = (lr & 8) ? fminf(v[k + 8], r) : fminf(v[k], r);
        }
        #pragma unroll
        for (int k = 0; k < 4; ++k) {
            float s = (lr & 4) ? v[k] : v[k + 4];
            float r = __shfl_xor(s, 4);
            v[k] = (lr & 4) ? fminf(v[k + 4], r) : fminf(v[k], r);
        }
        #pragma unroll
        for (int k = 0; k < 2; ++k) {
            float s = (lr & 2) ? v[k] : v[k + 2];
            float r = __shfl_xor(s, 2);
            v[k] = (lr & 2) ? fminf(v[k + 2], r) : fminf(v[k], r);
        }
        {
            float s = (lr & 1) ? v[0] : v[1];
            float r = __shfl_xor(s, 1);
            v[0] = (lr & 1) ? fminf(v[1], r) : fminf(v[0], r);
        }
        const int own_row = tm_base + wr + ((lr >> 2) << 4) + (lq << 2) + (lr & 3);

        float cp[4];
        #pragma unroll
        for (int ni = 0; ni < 4; ++ni) {
            float m = fmaf(-2.f, acc[0][ni][0], a2v[0][0]);
            #pragma unroll
            for (int mi = 0; mi < 4; ++mi)
                #pragma unroll
                for (int j = 0; j < 4; ++j)
                    if (mi | j) m = fminf(m, fmaf(-2.f, acc[mi][ni][j], a2v[mi][j]));
            cp[ni] = m;
        }
        #pragma unroll
        for (int k = 0; k < 2; ++k) {
            float s = (lane & 16) ? cp[k] : cp[k + 2];
            float r = __shfl_xor(s, 16);
            cp[k] = (lane & 16) ? fminf(cp[k + 2], r) : fminf(cp[k], r);
        }
        float cfin;
        {
            float s = (lane & 32) ? cp[0] : cp[1];
            float r = __shfl_xor(s, 32);
            cfin = (lane & 32) ? fminf(cp[1], r) : fminf(cp[0], r);
        }
        const int ni_own = ((lq & 1) << 1) | (lq >> 1);
        const int own_col = col_base + ni_own * 16 + lr;

        __syncthreads();

        atomicMin(&rowmin[own_row], fmap(v[0]));
        atomicMin(&colmin[own_col], fmap(cfin));
    }
}

__global__ void chamfer_finalize2(const unsigned* __restrict__ rowmin,
                                  const unsigned* __restrict__ colmin,
                                  const float* __restrict__ a2, const float* __restrict__ b2,
                                  float* __restrict__ out) {
    __shared__ double sred[16];
    int t = threadIdx.x;
    double s = 0.0;
    for (int i = t; i < N_PTS; i += 1024)
        s += ((double)funmap(rowmin[i]) + (double)a2[i])
           + ((double)funmap(colmin[i]) + (double)b2[i]);
    #pragma unroll
    for (int off = 32; off; off >>= 1) s += __shfl_down(s, off);
    if ((t & 63) == 0) sred[t >> 6] = s;
    __syncthreads();
    if (t == 0) {
        double tot = 0.0;
        #pragma unroll
        for (int i = 0; i < 16; ++i) tot += sred[i];
        out[0] = (float)(tot * (1.0 / (double)N_PTS));
    }
}

// ---------------------------------------------------------------------------
extern "C" void kernel_launch(void* const* d_in, const int* in_sizes, int n_in,
                              void* d_out, int out_size, void* d_ws, size_t ws_size,
                              hipStream_t stream) {
    const float* A = (const float*)d_in[0];
    const float* B = (const float*)d_in[1];
    float* out = (float*)d_out;
    char* ws = (char*)d_ws;

    const size_t SZ5   = (size_t)N_PTS * KAUG * sizeof(unsigned short);  // 4.72 MB
    const size_t need5 = 2 * SZ5 + 4 * (size_t)N_PTS * 4;                // ~9.7 MB

    const size_t BF    = (size_t)N_PTS * DIM * sizeof(unsigned short);   // 4 MB
    const size_t need3 = 2 * BF + 4 * (size_t)(1 << 16);                 // ~8.65 MB

    if (ws_size >= need5) {
        unsigned short* Ax = (unsigned short*)(ws);
        unsigned short* Bx = (unsigned short*)(ws + SZ5);
        unsigned* minbuf   = (unsigned*)(ws + 2 * SZ5);
        unsigned* rowminS  = minbuf;                     // [2][N]
        unsigned* colminS  = minbuf + 2 * N_PTS;         // [2][N]

        chamfer_prep5<<<(2 * N_PTS) / 4, 256, 0, stream>>>(A, B, Ax, Bx, minbuf);
        chamfer_gemm_min5<<<512, 256, 0, stream>>>(Ax, Bx, rowminS, colminS);
        chamfer_finalize4<<<1, 1024, 0, stream>>>(rowminS, colminS, out);
    } else if (ws_size >= need3) {
        unsigned short* Abf = (unsigned short*)(ws);
        unsigned short* Bbf = (unsigned short*)(ws + BF);
        float*    a2     = (float*)(ws + 2 * BF);
        float*    b2     = (float*)(ws + 2 * BF + (1 << 16));
        unsigned* rowmin = (unsigned*)(ws + 2 * BF + (2 << 16));
        unsigned* colmin = (unsigned*)(ws + 2 * BF + (3 << 16));

        chamfer_prep2<<<(2 * N_PTS) / 4, 256, 0, stream>>>(A, B, Abf, Bbf, a2, b2, rowmin, colmin);
        chamfer_gemm_min3<<<256, 512, 0, stream>>>(Abf, Bbf, a2, b2, rowmin, colmin);
        chamfer_finalize2<<<1, 1024, 0, stream>>>(rowmin, colmin, a2, b2, out);
    }
}